// Round 1
// baseline (1577.820 us; speedup 1.0000x reference)
//
#include <hip/hip_runtime.h>

#define DIM   1536
#define NQKV  4608
#define NH    24
#define HD    64
#define BATCH 4
#define SEQ   4096
#define ROWS  16384   // BATCH*SEQ

typedef _Float16 f16x8 __attribute__((ext_vector_type(8)));
typedef float    f32x4 __attribute__((ext_vector_type(4)));

__device__ __forceinline__ void gload_lds16(const void* g, void* l) {
  __builtin_amdgcn_global_load_lds(
      (const __attribute__((address_space(1))) unsigned int*)g,
      (__attribute__((address_space(3))) unsigned int*)l, 16, 0, 0);
}
__device__ __forceinline__ float fexp2(float x) {
#if __has_builtin(__builtin_amdgcn_exp2f)
  return __builtin_amdgcn_exp2f(x);
#else
  return exp2f(x);
#endif
}

// scale * log2(e), folded into q inside rms_rope
#define QSCALE 0.18033688011112042f

// ---------------- kernel 0: X fp32 -> fp16 --------------------------------
__global__ __launch_bounds__(256) void convert_x(const float* __restrict__ X,
                                                 _Float16* __restrict__ Xh) {
  const int i = (blockIdx.x * 256 + threadIdx.x) * 8;
  float4 a = *(const float4*)(X + i);
  float4 b = *(const float4*)(X + i + 4);
  f16x8 h;
  h[0] = (_Float16)a.x; h[1] = (_Float16)a.y; h[2] = (_Float16)a.z; h[3] = (_Float16)a.w;
  h[4] = (_Float16)b.x; h[5] = (_Float16)b.y; h[6] = (_Float16)b.z; h[7] = (_Float16)b.w;
  *(f16x8*)(Xh + i) = h;
}

// ---------------- kernel 1: W (K x N) fp32 -> Wt (N x K) fp16 -------------
__global__ __launch_bounds__(256) void transpose_w(const float* __restrict__ W,
                                                   _Float16* __restrict__ Wt) {
  __shared__ float tile[32][33];
  const int tx = threadIdx.x, ty = threadIdx.y;        // 32 x 8
  const int k0 = blockIdx.y * 32, n0 = blockIdx.x * 32;
  #pragma unroll
  for (int i = 0; i < 32; i += 8)
    tile[ty + i][tx] = W[(size_t)(k0 + ty + i) * NQKV + n0 + tx];
  __syncthreads();
  #pragma unroll
  for (int i = 0; i < 32; i += 8)
    Wt[(size_t)(n0 + ty + i) * DIM + k0 + tx] = (_Float16)tile[tx][ty + i];
}

// ---------------- kernel 2: QKV = Xh @ Wt^T + b  (fp16 MFMA) --------------
__global__ __launch_bounds__(256) void qkv_gemm(const _Float16* __restrict__ Xh,
                                                const _Float16* __restrict__ Wt,
                                                const float* __restrict__ Bias,
                                                _Float16* __restrict__ QKV) {
  __shared__ _Float16 As[128 * 64];
  __shared__ _Float16 Bs[128 * 64];
  const int w    = threadIdx.x >> 6;
  const int lane = threadIdx.x & 63;
  const int lr   = lane >> 3, lc = lane & 7;
  const int quad = lane >> 4, l15 = lane & 15;
  const int m0 = blockIdx.y * 128;
  const int n0 = blockIdx.x * 128;
  const int waveR = (w >> 1) * 64;
  const int waveC = (w & 1) * 64;

  f32x4 acc[4][4];
  #pragma unroll
  for (int i = 0; i < 4; i++)
    #pragma unroll
    for (int j = 0; j < 4; j++) acc[i][j] = (f32x4){0.f, 0.f, 0.f, 0.f};

  for (int kt = 0; kt < DIM / 64; ++kt) {
    const int k0 = kt * 64;
    #pragma unroll
    for (int i = 0; i < 4; ++i) {
      const int rr = w * 32 + i * 8;
      gload_lds16(Xh + (size_t)(m0 + rr + lr) * DIM + k0 + lc * 8, &As[rr * 64]);
      gload_lds16(Wt + (size_t)(n0 + rr + lr) * DIM + k0 + lc * 8, &Bs[rr * 64]);
    }
    __syncthreads();
    #pragma unroll
    for (int ks = 0; ks < 2; ++ks) {
      f16x8 aF[4], bF[4];
      #pragma unroll
      for (int t = 0; t < 4; t++)
        aF[t] = *(const f16x8*)&As[(waveR + t * 16 + l15) * 64 + ks * 32 + quad * 8];
      #pragma unroll
      for (int t = 0; t < 4; t++)
        bF[t] = *(const f16x8*)&Bs[(waveC + t * 16 + l15) * 64 + ks * 32 + quad * 8];
      #pragma unroll
      for (int mt = 0; mt < 4; mt++)
        #pragma unroll
        for (int nt = 0; nt < 4; nt++)
          acc[mt][nt] = __builtin_amdgcn_mfma_f32_16x16x32_f16(aF[mt], bF[nt], acc[mt][nt], 0, 0, 0);
    }
    __syncthreads();
  }
  #pragma unroll
  for (int nt = 0; nt < 4; nt++) {
    const int n = n0 + waveC + nt * 16 + l15;
    const float bias = Bias[n];
    #pragma unroll
    for (int mt = 0; mt < 4; mt++) {
      const int mBase = m0 + waveR + mt * 16 + quad * 4;
      #pragma unroll
      for (int r = 0; r < 4; r++)
        QKV[(size_t)(mBase + r) * NQKV + n] = (_Float16)(acc[mt][nt][r] + bias);
    }
  }
}

// ---------------- kernel 3: RMSNorm(q,k) + RoPE, in place -----------------
__global__ __launch_bounds__(256) void rms_rope(_Float16* __restrict__ QKV,
                                                const float* __restrict__ Cos,
                                                const float* __restrict__ Sin) {
  const int gw   = blockIdx.x * 4 + (threadIdx.x >> 6);
  const int lane = threadIdx.x & 63;
  const int row  = gw / NH;
  const int h    = gw - row * NH;
  const int s    = row & (SEQ - 1);

  _Float16* p = QKV + (size_t)row * NQKV + h * HD;
  float q = (float)p[lane];
  float k = (float)p[DIM + lane];

  float sq = q * q, sk = k * k;
  #pragma unroll
  for (int off = 1; off < 64; off <<= 1) {
    sq += __shfl_xor(sq, off);
    sk += __shfl_xor(sk, off);
  }
  q *= rsqrtf(sq * (1.f / 64.f) + 1e-6f);
  k *= rsqrtf(sk * (1.f / 64.f) + 1e-6f);

  const float c  = Cos[s * HD + lane];
  const float si = Sin[s * HD + lane];
  const float qp = __shfl_xor(q, 1);
  const float kp = __shfl_xor(k, 1);
  float oq, ok;
  if (lane & 1) { oq = q * c + qp * si; ok = k * c + kp * si; }
  else          { oq = q * c - qp * si; ok = k * c - kp * si; }

  p[lane]       = (_Float16)(oq * QSCALE);
  p[DIM + lane] = (_Float16)ok;
}

// ---------------- kernel 4: flash attention, static-max softmax -----------
// BR=128 (32 q-rows per wave), Q in registers, p=exp2(score) with no max
// tracking, row-sum via ones-column MFMA.
// R1: T14 async-STAGE split (prefetch next K/V tile into regs during compute)
//     + T5 setprio around MFMA clusters.
#define LSTR 72
#define NT   (SEQ / 64)
__global__ __launch_bounds__(256, 4) void flash_attn(const _Float16* __restrict__ QKV,
                                                     float* __restrict__ Out) {
  __shared__ __align__(16) _Float16 sm[2 * 64 * LSTR + 4 * 32 * LSTR];
  _Float16* Ks  = sm;
  _Float16* Vts = sm + 64 * LSTR;
  const int w = threadIdx.x >> 6;
  _Float16* Ps = sm + 2 * 64 * LSTR + w * 32 * LSTR;   // wave-private
  const int lane = threadIdx.x & 63;
  const int quad = lane >> 4, l15 = lane & 15;
  const int bh = blockIdx.y;
  const int qt = blockIdx.x;
  const int b  = bh / NH;
  const int h  = bh - b * NH;
  const size_t rowb = (size_t)b * SEQ * NQKV + (size_t)h * HD;  // + s*NQKV per token

  // K-stage addressing (per thread, constant over the loop)
  const int kchunk0 = threadIdx.x;            // chunk = tid + i*256
  // V-stage addressing
  // (c0 = w*16 + i*8; row = lane)

  // Q fragments (A-layout) straight from global into registers, kept all loop
  f16x8 qreg[2][2];
  #pragma unroll
  for (int mt = 0; mt < 2; mt++)
    #pragma unroll
    for (int ks = 0; ks < 2; ks++) {
      const int row = qt * 128 + w * 32 + mt * 16 + l15;
      qreg[mt][ks] = *(const f16x8*)(QKV + rowb + (size_t)row * NQKV + ks * 32 + quad * 8);
    }

  // ones B-fragment: column n==0 of the ghost V-tile is all ones
  f16x8 onesF;
  {
    const _Float16 one = (_Float16)(l15 == 0 ? 1.0f : 0.0f);
    #pragma unroll
    for (int j = 0; j < 8; j++) onesF[j] = one;
  }

  f32x4 o[2][4], o4[2];
  #pragma unroll
  for (int mt = 0; mt < 2; mt++) {
    o4[mt] = (f32x4){0.f, 0.f, 0.f, 0.f};
    #pragma unroll
    for (int t = 0; t < 4; t++) o[mt][t] = (f32x4){0.f, 0.f, 0.f, 0.f};
  }

  // ---- prologue: prefetch tile 0 into registers --------------------------
  uint4 kpre[2], vpre[2];
  #pragma unroll
  for (int i = 0; i < 2; i++) {
    const int chunk = kchunk0 + i * 256;
    const int r = chunk >> 3, c0 = (chunk & 7) * 8;
    kpre[i] = *(const uint4*)(QKV + rowb + (size_t)r * NQKV + DIM + c0);
  }
  #pragma unroll
  for (int i = 0; i < 2; i++) {
    const int c0 = w * 16 + i * 8;
    vpre[i] = *(const uint4*)(QKV + rowb + (size_t)lane * NQKV + 2 * DIM + c0);
  }

  for (int kt = 0; kt < NT; ++kt) {
    __syncthreads();   // previous iteration's LDS reads complete
    // ---- commit staged registers to LDS ----------------------------------
    #pragma unroll
    for (int i = 0; i < 2; i++) {
      const int chunk = kchunk0 + i * 256;
      const int r = chunk >> 3, c0 = (chunk & 7) * 8;
      *(uint4*)&Ks[r * LSTR + c0] = kpre[i];
    }
    #pragma unroll
    for (int i = 0; i < 2; i++) {
      const int c0 = w * 16 + i * 8;
      union { uint4 v; _Float16 u[8]; } d;
      d.v = vpre[i];
      #pragma unroll
      for (int j = 0; j < 8; j++) Vts[(c0 + j) * LSTR + lane] = d.u[j];
    }
    __syncthreads();

    // ---- issue next tile's global loads (latency hides under compute) ----
    {
      const int ktn = (kt + 1 < NT) ? kt + 1 : kt;
      #pragma unroll
      for (int i = 0; i < 2; i++) {
        const int chunk = kchunk0 + i * 256;
        const int r = chunk >> 3, c0 = (chunk & 7) * 8;
        kpre[i] = *(const uint4*)(QKV + rowb + (size_t)(ktn * 64 + r) * NQKV + DIM + c0);
      }
      #pragma unroll
      for (int i = 0; i < 2; i++) {
        const int c0 = w * 16 + i * 8;
        vpre[i] = *(const uint4*)(QKV + rowb + (size_t)(ktn * 64 + lane) * NQKV + 2 * DIM + c0);
      }
    }

    // S = Q K^T : 32 q-rows x 64 keys per wave (scores already in log2 domain)
    f32x4 sacc[2][4];
    #pragma unroll
    for (int mt = 0; mt < 2; mt++)
      #pragma unroll
      for (int t = 0; t < 4; t++) sacc[mt][t] = (f32x4){0.f, 0.f, 0.f, 0.f};
    __builtin_amdgcn_s_setprio(1);
    #pragma unroll
    for (int ks = 0; ks < 2; ks++) {
      f16x8 bF[4];
      #pragma unroll
      for (int t = 0; t < 4; t++)
        bF[t] = *(const f16x8*)&Ks[(t * 16 + l15) * LSTR + ks * 32 + quad * 8];
      #pragma unroll
      for (int mt = 0; mt < 2; mt++)
        #pragma unroll
        for (int t = 0; t < 4; t++)
          sacc[mt][t] = __builtin_amdgcn_mfma_f32_16x16x32_f16(qreg[mt][ks], bF[t], sacc[mt][t], 0, 0, 0);
    }
    __builtin_amdgcn_s_setprio(0);

    // p = exp2(score); write fp16 P to wave-private LDS (no max, no rescale)
    #pragma unroll
    for (int mt = 0; mt < 2; mt++)
      #pragma unroll
      for (int t = 0; t < 4; t++)
        #pragma unroll
        for (int r = 0; r < 4; r++) {
          const _Float16 ph = (_Float16)fexp2(sacc[mt][t][r]);
          Ps[(mt * 16 + quad * 4 + r) * LSTR + t * 16 + l15] = ph;
        }

    // O += P V ; Sigma p (rounded) via ones-column into o4
    __builtin_amdgcn_s_setprio(1);
    #pragma unroll
    for (int ks = 0; ks < 2; ks++) {
      f16x8 pF[2];
      #pragma unroll
      for (int mt = 0; mt < 2; mt++)
        pF[mt] = *(const f16x8*)&Ps[(mt * 16 + l15) * LSTR + ks * 32 + quad * 8];
      #pragma unroll
      for (int t = 0; t < 4; t++) {
        f16x8 vF = *(const f16x8*)&Vts[(t * 16 + l15) * LSTR + ks * 32 + quad * 8];
        #pragma unroll
        for (int mt = 0; mt < 2; mt++)
          o[mt][t] = __builtin_amdgcn_mfma_f32_16x16x32_f16(pF[mt], vF, o[mt][t], 0, 0, 0);
      }
      #pragma unroll
      for (int mt = 0; mt < 2; mt++)
        o4[mt] = __builtin_amdgcn_mfma_f32_16x16x32_f16(pF[mt], onesF, o4[mt], 0, 0, 0);
    }
    __builtin_amdgcn_s_setprio(0);
  }

  // epilogue: lrow = Sigma p lives at lanes l15==0 (col 0 of ones-tile)
  #pragma unroll
  for (int mt = 0; mt < 2; mt++) {
    float lrow[4];
    #pragma unroll
    for (int r = 0; r < 4; r++) lrow[r] = __shfl(o4[mt][r], lane & 48);
    #pragma unroll
    for (int t = 0; t < 4; t++)
      #pragma unroll
      for (int r = 0; r < 4; r++) {
        const int srow = qt * 128 + w * 32 + mt * 16 + quad * 4 + r;
        const int d = t * 16 + l15;
        Out[((size_t)(b * SEQ + srow)) * DIM + h * HD + d] = o[mt][t][r] / lrow[r];
      }
  }
}

// ---------------- launch --------------------------------------------------
extern "C" void kernel_launch(void* const* d_in, const int* in_sizes, int n_in,
                              void* d_out, int out_size, void* d_ws, size_t ws_size,
                              hipStream_t stream) {
  const float* X    = (const float*)d_in[0];
  const float* Cos  = (const float*)d_in[1];
  const float* Sin  = (const float*)d_in[2];
  const float* W    = (const float*)d_in[3];
  const float* Bias = (const float*)d_in[4];
  float* Out = (float*)d_out;

  char* ws = (char*)d_ws;
  _Float16* Xh  = (_Float16*)(ws);                  // 50,331,648 B
  _Float16* Wt  = (_Float16*)(ws + 50331648);       // 14,155,776 B
  _Float16* QKV = (_Float16*)(ws + 64487424);       // 150,994,944 B (end 215,482,368)

  convert_x  <<<dim3(ROWS * DIM / (8 * 256)), 256, 0, stream>>>(X, Xh);
  transpose_w<<<dim3(NQKV / 32, DIM / 32), dim3(32, 8), 0, stream>>>(W, Wt);
  qkv_gemm   <<<dim3(NQKV / 128, ROWS / 128), 256, 0, stream>>>(Xh, Wt, Bias, QKV);
  rms_rope   <<<dim3(ROWS * NH / 4), 256, 0, stream>>>(QKV, Cos, Sin);
  flash_attn <<<dim3(SEQ / 128, BATCH * NH), 256, 0, stream>>>(QKV, Out);
}

// Round 2
// 1459.447 us; speedup vs baseline: 1.0811x; 1.0811x over previous
//
#include <hip/hip_runtime.h>

#define DIM   1536
#define NQKV  4608
#define NH    24
#define HD    64
#define BATCH 4
#define SEQ   4096
#define ROWS  16384   // BATCH*SEQ

typedef _Float16 f16x8 __attribute__((ext_vector_type(8)));
typedef float    f32x4 __attribute__((ext_vector_type(4)));

__device__ __forceinline__ void gload_lds16(const void* g, void* l) {
  __builtin_amdgcn_global_load_lds(
      (const __attribute__((address_space(1))) unsigned int*)g,
      (__attribute__((address_space(3))) unsigned int*)l, 16, 0, 0);
}
__device__ __forceinline__ float fexp2(float x) {
#if __has_builtin(__builtin_amdgcn_exp2f)
  return __builtin_amdgcn_exp2f(x);
#else
  return exp2f(x);
#endif
}

// scale * log2(e), folded into q inside rms_rope
#define QSCALE 0.18033688011112042f

// ---------------- kernel 0: X fp32 -> fp16 --------------------------------
__global__ __launch_bounds__(256) void convert_x(const float* __restrict__ X,
                                                 _Float16* __restrict__ Xh) {
  const int i = (blockIdx.x * 256 + threadIdx.x) * 8;
  float4 a = *(const float4*)(X + i);
  float4 b = *(const float4*)(X + i + 4);
  f16x8 h;
  h[0] = (_Float16)a.x; h[1] = (_Float16)a.y; h[2] = (_Float16)a.z; h[3] = (_Float16)a.w;
  h[4] = (_Float16)b.x; h[5] = (_Float16)b.y; h[6] = (_Float16)b.z; h[7] = (_Float16)b.w;
  *(f16x8*)(Xh + i) = h;
}

// ---------------- kernel 1: W (K x N) fp32 -> Wt (N x K) fp16 -------------
__global__ __launch_bounds__(256) void transpose_w(const float* __restrict__ W,
                                                   _Float16* __restrict__ Wt) {
  __shared__ float tile[32][33];
  const int tx = threadIdx.x, ty = threadIdx.y;        // 32 x 8
  const int k0 = blockIdx.y * 32, n0 = blockIdx.x * 32;
  #pragma unroll
  for (int i = 0; i < 32; i += 8)
    tile[ty + i][tx] = W[(size_t)(k0 + ty + i) * NQKV + n0 + tx];
  __syncthreads();
  #pragma unroll
  for (int i = 0; i < 32; i += 8)
    Wt[(size_t)(n0 + ty + i) * DIM + k0 + tx] = (_Float16)tile[tx][ty + i];
}

// ---------------- kernel 2: QKV = Xh @ Wt^T + b  (fp16 MFMA) --------------
__global__ __launch_bounds__(256) void qkv_gemm(const _Float16* __restrict__ Xh,
                                                const _Float16* __restrict__ Wt,
                                                const float* __restrict__ Bias,
                                                _Float16* __restrict__ QKV) {
  __shared__ _Float16 As[128 * 64];
  __shared__ _Float16 Bs[128 * 64];
  const int w    = threadIdx.x >> 6;
  const int lane = threadIdx.x & 63;
  const int lr   = lane >> 3, lc = lane & 7;
  const int quad = lane >> 4, l15 = lane & 15;
  const int m0 = blockIdx.y * 128;
  const int n0 = blockIdx.x * 128;
  const int waveR = (w >> 1) * 64;
  const int waveC = (w & 1) * 64;

  f32x4 acc[4][4];
  #pragma unroll
  for (int i = 0; i < 4; i++)
    #pragma unroll
    for (int j = 0; j < 4; j++) acc[i][j] = (f32x4){0.f, 0.f, 0.f, 0.f};

  for (int kt = 0; kt < DIM / 64; ++kt) {
    const int k0 = kt * 64;
    #pragma unroll
    for (int i = 0; i < 4; ++i) {
      const int rr = w * 32 + i * 8;
      gload_lds16(Xh + (size_t)(m0 + rr + lr) * DIM + k0 + lc * 8, &As[rr * 64]);
      gload_lds16(Wt + (size_t)(n0 + rr + lr) * DIM + k0 + lc * 8, &Bs[rr * 64]);
    }
    __syncthreads();
    #pragma unroll
    for (int ks = 0; ks < 2; ++ks) {
      f16x8 aF[4], bF[4];
      #pragma unroll
      for (int t = 0; t < 4; t++)
        aF[t] = *(const f16x8*)&As[(waveR + t * 16 + l15) * 64 + ks * 32 + quad * 8];
      #pragma unroll
      for (int t = 0; t < 4; t++)
        bF[t] = *(const f16x8*)&Bs[(waveC + t * 16 + l15) * 64 + ks * 32 + quad * 8];
      #pragma unroll
      for (int mt = 0; mt < 4; mt++)
        #pragma unroll
        for (int nt = 0; nt < 4; nt++)
          acc[mt][nt] = __builtin_amdgcn_mfma_f32_16x16x32_f16(aF[mt], bF[nt], acc[mt][nt], 0, 0, 0);
    }
    __syncthreads();
  }
  #pragma unroll
  for (int nt = 0; nt < 4; nt++) {
    const int n = n0 + waveC + nt * 16 + l15;
    const float bias = Bias[n];
    #pragma unroll
    for (int mt = 0; mt < 4; mt++) {
      const int mBase = m0 + waveR + mt * 16 + quad * 4;
      #pragma unroll
      for (int r = 0; r < 4; r++)
        QKV[(size_t)(mBase + r) * NQKV + n] = (_Float16)(acc[mt][nt][r] + bias);
    }
  }
}

// ---------------- kernel 3: RMSNorm(q,k) + RoPE, in place -----------------
__global__ __launch_bounds__(256) void rms_rope(_Float16* __restrict__ QKV,
                                                const float* __restrict__ Cos,
                                                const float* __restrict__ Sin) {
  const int gw   = blockIdx.x * 4 + (threadIdx.x >> 6);
  const int lane = threadIdx.x & 63;
  const int row  = gw / NH;
  const int h    = gw - row * NH;
  const int s    = row & (SEQ - 1);

  _Float16* p = QKV + (size_t)row * NQKV + h * HD;
  float q = (float)p[lane];
  float k = (float)p[DIM + lane];

  float sq = q * q, sk = k * k;
  #pragma unroll
  for (int off = 1; off < 64; off <<= 1) {
    sq += __shfl_xor(sq, off);
    sk += __shfl_xor(sk, off);
  }
  q *= rsqrtf(sq * (1.f / 64.f) + 1e-6f);
  k *= rsqrtf(sk * (1.f / 64.f) + 1e-6f);

  const float c  = Cos[s * HD + lane];
  const float si = Sin[s * HD + lane];
  const float qp = __shfl_xor(q, 1);
  const float kp = __shfl_xor(k, 1);
  float oq, ok;
  if (lane & 1) { oq = q * c + qp * si; ok = k * c + kp * si; }
  else          { oq = q * c - qp * si; ok = k * c - kp * si; }

  p[lane]       = (_Float16)(oq * QSCALE);
  p[DIM + lane] = (_Float16)ok;
}

// ---------------- kernel 4: flash attention, static-max softmax -----------
// BR=128 (32 q-rows per wave), Q in registers, p=exp2(score) with no max
// tracking, row-sum via ones-column MFMA.
// R2: T14 async-STAGE split kept, but WITHOUT the min-waves launch bound
//     (R1's __launch_bounds__(256,4) capped VGPRs at 64 and spilled the
//     prefetch state to scratch: WRITE_SIZE 98MB->1.6GB. LDS already limits
//     occupancy to 4 blocks/CU, so the bound bought nothing.)
#define LSTR 72
#define NT   (SEQ / 64)
__global__ __launch_bounds__(256) void flash_attn(const _Float16* __restrict__ QKV,
                                                  float* __restrict__ Out) {
  __shared__ __align__(16) _Float16 sm[2 * 64 * LSTR + 4 * 32 * LSTR];
  _Float16* Ks  = sm;
  _Float16* Vts = sm + 64 * LSTR;
  const int w = threadIdx.x >> 6;
  _Float16* Ps = sm + 2 * 64 * LSTR + w * 32 * LSTR;   // wave-private
  const int lane = threadIdx.x & 63;
  const int quad = lane >> 4, l15 = lane & 15;
  const int bh = blockIdx.y;
  const int qt = blockIdx.x;
  const int b  = bh / NH;
  const int h  = bh - b * NH;
  const size_t rowb = (size_t)b * SEQ * NQKV + (size_t)h * HD;  // + s*NQKV per token

  const int kchunk0 = threadIdx.x;            // K-stage: chunk = tid + i*256

  // Q fragments (A-layout) straight from global into registers, kept all loop
  f16x8 qreg[2][2];
  #pragma unroll
  for (int mt = 0; mt < 2; mt++)
    #pragma unroll
    for (int ks = 0; ks < 2; ks++) {
      const int row = qt * 128 + w * 32 + mt * 16 + l15;
      qreg[mt][ks] = *(const f16x8*)(QKV + rowb + (size_t)row * NQKV + ks * 32 + quad * 8);
    }

  // ones B-fragment: column n==0 of the ghost V-tile is all ones
  f16x8 onesF;
  {
    const _Float16 one = (_Float16)(l15 == 0 ? 1.0f : 0.0f);
    #pragma unroll
    for (int j = 0; j < 8; j++) onesF[j] = one;
  }

  f32x4 o[2][4], o4[2];
  #pragma unroll
  for (int mt = 0; mt < 2; mt++) {
    o4[mt] = (f32x4){0.f, 0.f, 0.f, 0.f};
    #pragma unroll
    for (int t = 0; t < 4; t++) o[mt][t] = (f32x4){0.f, 0.f, 0.f, 0.f};
  }

  // ---- prologue: prefetch tile 0 into registers --------------------------
  uint4 kpre[2], vpre[2];
  #pragma unroll
  for (int i = 0; i < 2; i++) {
    const int chunk = kchunk0 + i * 256;
    const int r = chunk >> 3, c0 = (chunk & 7) * 8;
    kpre[i] = *(const uint4*)(QKV + rowb + (size_t)r * NQKV + DIM + c0);
  }
  #pragma unroll
  for (int i = 0; i < 2; i++) {
    const int c0 = w * 16 + i * 8;
    vpre[i] = *(const uint4*)(QKV + rowb + (size_t)lane * NQKV + 2 * DIM + c0);
  }

  for (int kt = 0; kt < NT; ++kt) {
    __syncthreads();   // previous iteration's LDS reads complete
    // ---- commit staged registers to LDS ----------------------------------
    #pragma unroll
    for (int i = 0; i < 2; i++) {
      const int chunk = kchunk0 + i * 256;
      const int r = chunk >> 3, c0 = (chunk & 7) * 8;
      *(uint4*)&Ks[r * LSTR + c0] = kpre[i];
    }
    #pragma unroll
    for (int i = 0; i < 2; i++) {
      const int c0 = w * 16 + i * 8;
      union { uint4 v; _Float16 u[8]; } d;
      d.v = vpre[i];
      #pragma unroll
      for (int j = 0; j < 8; j++) Vts[(c0 + j) * LSTR + lane] = d.u[j];
    }
    __syncthreads();

    // ---- issue next tile's global loads (latency hides under compute) ----
    {
      const int ktn = (kt + 1 < NT) ? kt + 1 : kt;
      #pragma unroll
      for (int i = 0; i < 2; i++) {
        const int chunk = kchunk0 + i * 256;
        const int r = chunk >> 3, c0 = (chunk & 7) * 8;
        kpre[i] = *(const uint4*)(QKV + rowb + (size_t)(ktn * 64 + r) * NQKV + DIM + c0);
      }
      #pragma unroll
      for (int i = 0; i < 2; i++) {
        const int c0 = w * 16 + i * 8;
        vpre[i] = *(const uint4*)(QKV + rowb + (size_t)(ktn * 64 + lane) * NQKV + 2 * DIM + c0);
      }
    }

    // S = Q K^T : 32 q-rows x 64 keys per wave (scores already in log2 domain)
    f32x4 sacc[2][4];
    #pragma unroll
    for (int mt = 0; mt < 2; mt++)
      #pragma unroll
      for (int t = 0; t < 4; t++) sacc[mt][t] = (f32x4){0.f, 0.f, 0.f, 0.f};
    __builtin_amdgcn_s_setprio(1);
    #pragma unroll
    for (int ks = 0; ks < 2; ks++) {
      f16x8 bF[4];
      #pragma unroll
      for (int t = 0; t < 4; t++)
        bF[t] = *(const f16x8*)&Ks[(t * 16 + l15) * LSTR + ks * 32 + quad * 8];
      #pragma unroll
      for (int mt = 0; mt < 2; mt++)
        #pragma unroll
        for (int t = 0; t < 4; t++)
          sacc[mt][t] = __builtin_amdgcn_mfma_f32_16x16x32_f16(qreg[mt][ks], bF[t], sacc[mt][t], 0, 0, 0);
    }
    __builtin_amdgcn_s_setprio(0);

    // p = exp2(score); write fp16 P to wave-private LDS (no max, no rescale)
    #pragma unroll
    for (int mt = 0; mt < 2; mt++)
      #pragma unroll
      for (int t = 0; t < 4; t++)
        #pragma unroll
        for (int r = 0; r < 4; r++) {
          const _Float16 ph = (_Float16)fexp2(sacc[mt][t][r]);
          Ps[(mt * 16 + quad * 4 + r) * LSTR + t * 16 + l15] = ph;
        }

    // O += P V ; Sigma p (rounded) via ones-column into o4
    __builtin_amdgcn_s_setprio(1);
    #pragma unroll
    for (int ks = 0; ks < 2; ks++) {
      f16x8 pF[2];
      #pragma unroll
      for (int mt = 0; mt < 2; mt++)
        pF[mt] = *(const f16x8*)&Ps[(mt * 16 + l15) * LSTR + ks * 32 + quad * 8];
      #pragma unroll
      for (int t = 0; t < 4; t++) {
        f16x8 vF = *(const f16x8*)&Vts[(t * 16 + l15) * LSTR + ks * 32 + quad * 8];
        #pragma unroll
        for (int mt = 0; mt < 2; mt++)
          o[mt][t] = __builtin_amdgcn_mfma_f32_16x16x32_f16(pF[mt], vF, o[mt][t], 0, 0, 0);
      }
      #pragma unroll
      for (int mt = 0; mt < 2; mt++)
        o4[mt] = __builtin_amdgcn_mfma_f32_16x16x32_f16(pF[mt], onesF, o4[mt], 0, 0, 0);
    }
    __builtin_amdgcn_s_setprio(0);
  }

  // epilogue: lrow = Sigma p lives at lanes l15==0 (col 0 of ones-tile)
  #pragma unroll
  for (int mt = 0; mt < 2; mt++) {
    float lrow[4];
    #pragma unroll
    for (int r = 0; r < 4; r++) lrow[r] = __shfl(o4[mt][r], lane & 48);
    #pragma unroll
    for (int t = 0; t < 4; t++)
      #pragma unroll
      for (int r = 0; r < 4; r++) {
        const int srow = qt * 128 + w * 32 + mt * 16 + quad * 4 + r;
        const int d = t * 16 + l15;
        Out[((size_t)(b * SEQ + srow)) * DIM + h * HD + d] = o[mt][t][r] / lrow[r];
      }
  }
}

// ---------------- launch --------------------------------------------------
extern "C" void kernel_launch(void* const* d_in, const int* in_sizes, int n_in,
                              void* d_out, int out_size, void* d_ws, size_t ws_size,
                              hipStream_t stream) {
  const float* X    = (const float*)d_in[0];
  const float* Cos  = (const float*)d_in[1];
  const float* Sin  = (const float*)d_in[2];
  const float* W    = (const float*)d_in[3];
  const float* Bias = (const float*)d_in[4];
  float* Out = (float*)d_out;

  char* ws = (char*)d_ws;
  _Float16* Xh  = (_Float16*)(ws);                  // 50,331,648 B
  _Float16* Wt  = (_Float16*)(ws + 50331648);       // 14,155,776 B
  _Float16* QKV = (_Float16*)(ws + 64487424);       // 150,994,944 B (end 215,482,368)

  convert_x  <<<dim3(ROWS * DIM / (8 * 256)), 256, 0, stream>>>(X, Xh);
  transpose_w<<<dim3(NQKV / 32, DIM / 32), dim3(32, 8), 0, stream>>>(W, Wt);
  qkv_gemm   <<<dim3(NQKV / 128, ROWS / 128), 256, 0, stream>>>(Xh, Wt, Bias, QKV);
  rms_rope   <<<dim3(ROWS * NH / 4), 256, 0, stream>>>(QKV, Cos, Sin);
  flash_attn <<<dim3(SEQ / 128, BATCH * NH), 256, 0, stream>>>(QKV, Out);
}

// Round 3
// 1318.068 us; speedup vs baseline: 1.1971x; 1.1073x over previous
//
#include <hip/hip_runtime.h>

#define DIM   1536
#define NQKV  4608
#define NH    24
#define HD    64
#define BATCH 4
#define SEQ   4096
#define ROWS  16384   // BATCH*SEQ

typedef _Float16 f16x8 __attribute__((ext_vector_type(8)));
typedef float    f32x4 __attribute__((ext_vector_type(4)));

__device__ __forceinline__ void gload_lds16(const void* g, void* l) {
  __builtin_amdgcn_global_load_lds(
      (const __attribute__((address_space(1))) unsigned int*)g,
      (__attribute__((address_space(3))) unsigned int*)l, 16, 0, 0);
}
__device__ __forceinline__ float fexp2(float x) {
#if __has_builtin(__builtin_amdgcn_exp2f)
  return __builtin_amdgcn_exp2f(x);
#else
  return exp2f(x);
#endif
}

// scale * log2(e), folded into q inside the qkv_gemm epilogue
#define QSCALE 0.18033688011112042f

// ---------------- kernel 0: X fp32 -> fp16 --------------------------------
__global__ __launch_bounds__(256) void convert_x(const float* __restrict__ X,
                                                 _Float16* __restrict__ Xh) {
  const int i = (blockIdx.x * 256 + threadIdx.x) * 8;
  float4 a = *(const float4*)(X + i);
  float4 b = *(const float4*)(X + i + 4);
  f16x8 h;
  h[0] = (_Float16)a.x; h[1] = (_Float16)a.y; h[2] = (_Float16)a.z; h[3] = (_Float16)a.w;
  h[4] = (_Float16)b.x; h[5] = (_Float16)b.y; h[6] = (_Float16)b.z; h[7] = (_Float16)b.w;
  *(f16x8*)(Xh + i) = h;
}

// ---------------- kernel 1: W (K x N) fp32 -> Wt (N x K) fp16 -------------
__global__ __launch_bounds__(256) void transpose_w(const float* __restrict__ W,
                                                   _Float16* __restrict__ Wt) {
  __shared__ float tile[32][33];
  const int tx = threadIdx.x, ty = threadIdx.y;        // 32 x 8
  const int k0 = blockIdx.y * 32, n0 = blockIdx.x * 32;
  #pragma unroll
  for (int i = 0; i < 32; i += 8)
    tile[ty + i][tx] = W[(size_t)(k0 + ty + i) * NQKV + n0 + tx];
  __syncthreads();
  #pragma unroll
  for (int i = 0; i < 32; i += 8)
    Wt[(size_t)(n0 + ty + i) * DIM + k0 + tx] = (_Float16)tile[tx][ty + i];
}

// ---------------- kernel 2: QKV = Xh @ Wt^T + b, fused RMSNorm+RoPE -------
// R3: rms_rope fused into the epilogue. A wave's 64 output columns are
// exactly one head (n0 % 128 == 0, waveC in {0,64}), and a row's 64 head
// elements live in the 16-lane l15 group x 4 nt regs:
//   RMS  = sum over nt + shfl_xor{1,2,4,8} (stays inside the l15 group)
//   RoPE = partner d^1 is lane l15^1, same nt -> shfl_xor(x,1)
// Q additionally scaled by QSCALE (scores computed in log2 domain later).
__global__ __launch_bounds__(256) void qkv_gemm(const _Float16* __restrict__ Xh,
                                                const _Float16* __restrict__ Wt,
                                                const float* __restrict__ Bias,
                                                const float* __restrict__ Cos,
                                                const float* __restrict__ Sin,
                                                _Float16* __restrict__ QKV) {
  __shared__ _Float16 As[128 * 64];
  __shared__ _Float16 Bs[128 * 64];
  const int w    = threadIdx.x >> 6;
  const int lane = threadIdx.x & 63;
  const int lr   = lane >> 3, lc = lane & 7;
  const int quad = lane >> 4, l15 = lane & 15;
  const int m0 = blockIdx.y * 128;
  const int n0 = blockIdx.x * 128;
  const int waveR = (w >> 1) * 64;
  const int waveC = (w & 1) * 64;

  f32x4 acc[4][4];
  #pragma unroll
  for (int i = 0; i < 4; i++)
    #pragma unroll
    for (int j = 0; j < 4; j++) acc[i][j] = (f32x4){0.f, 0.f, 0.f, 0.f};

  for (int kt = 0; kt < DIM / 64; ++kt) {
    const int k0 = kt * 64;
    #pragma unroll
    for (int i = 0; i < 4; ++i) {
      const int rr = w * 32 + i * 8;
      gload_lds16(Xh + (size_t)(m0 + rr + lr) * DIM + k0 + lc * 8, &As[rr * 64]);
      gload_lds16(Wt + (size_t)(n0 + rr + lr) * DIM + k0 + lc * 8, &Bs[rr * 64]);
    }
    __syncthreads();
    #pragma unroll
    for (int ks = 0; ks < 2; ++ks) {
      f16x8 aF[4], bF[4];
      #pragma unroll
      for (int t = 0; t < 4; t++)
        aF[t] = *(const f16x8*)&As[(waveR + t * 16 + l15) * 64 + ks * 32 + quad * 8];
      #pragma unroll
      for (int t = 0; t < 4; t++)
        bF[t] = *(const f16x8*)&Bs[(waveC + t * 16 + l15) * 64 + ks * 32 + quad * 8];
      #pragma unroll
      for (int mt = 0; mt < 4; mt++)
        #pragma unroll
        for (int nt = 0; nt < 4; nt++)
          acc[mt][nt] = __builtin_amdgcn_mfma_f32_16x16x32_f16(aF[mt], bF[nt], acc[mt][nt], 0, 0, 0);
    }
    __syncthreads();
  }

  // ---- epilogue ----------------------------------------------------------
  const int nCol0  = n0 + waveC;          // wave's 64-col head base
  const int region = nCol0 / DIM;         // 0=Q, 1=K, 2=V (wave-uniform)

  float bias[4];
  #pragma unroll
  for (int nt = 0; nt < 4; nt++) bias[nt] = Bias[nCol0 + nt * 16 + l15];

  if (region == 2) {
    #pragma unroll
    for (int nt = 0; nt < 4; nt++) {
      const int n = nCol0 + nt * 16 + l15;
      #pragma unroll
      for (int mt = 0; mt < 4; mt++) {
        const int mBase = m0 + waveR + mt * 16 + quad * 4;
        #pragma unroll
        for (int r = 0; r < 4; r++)
          QKV[(size_t)(mBase + r) * NQKV + n] = (_Float16)(acc[mt][nt][r] + bias[nt]);
      }
    }
  } else {
    const float qsc = (region == 0) ? QSCALE : 1.0f;
    #pragma unroll
    for (int mt = 0; mt < 4; mt++) {
      const int mBase = m0 + waveR + mt * 16 + quad * 4;
      #pragma unroll
      for (int r = 0; r < 4; r++) {
        const int m = mBase + r;
        const int s = m & (SEQ - 1);
        float v[4];
        float ss = 0.f;
        #pragma unroll
        for (int nt = 0; nt < 4; nt++) {
          v[nt] = acc[mt][nt][r] + bias[nt];
          ss += v[nt] * v[nt];
        }
        #pragma unroll
        for (int off = 1; off < 16; off <<= 1) ss += __shfl_xor(ss, off);
        const float rinv = rsqrtf(ss * (1.f / 64.f) + 1e-6f);
        #pragma unroll
        for (int nt = 0; nt < 4; nt++) {
          const int d = nt * 16 + l15;
          const float c  = Cos[s * HD + d];
          const float si = Sin[s * HD + d];
          const float x  = v[nt] * rinv;
          const float xp = __shfl_xor(x, 1);
          float o = (l15 & 1) ? (x * c + xp * si) : (x * c - xp * si);
          o *= qsc;
          QKV[(size_t)m * NQKV + nCol0 + d] = (_Float16)o;
        }
      }
    }
  }
}

// ---------------- kernel 3: flash attention, static-max softmax -----------
// BR=128 (32 q-rows per wave), Q in registers, p=exp2(score) with no max
// tracking, row-sum via ones-column MFMA.
// R3: exact R0-baseline loop (T14/T5 reverted — both measured net-negative
// here) + T1 XCD-chunked block swizzle: the 32 q-blocks sharing one (b,h)'s
// K/V panel land on ONE XCD (4 active heads/XCD ~= 4MB L2), instead of
// round-robining each panel across all 8 per-XCD L2s.
#define LSTR 72
#define NBLK (SEQ / 128 * BATCH * NH)   // 3072, divisible by 8
__global__ __launch_bounds__(256) void flash_attn(const _Float16* __restrict__ QKV,
                                                  float* __restrict__ Out) {
  __shared__ __align__(16) _Float16 sm[2 * 64 * LSTR + 4 * 32 * LSTR];
  _Float16* Ks  = sm;
  _Float16* Vts = sm + 64 * LSTR;
  const int w = threadIdx.x >> 6;
  _Float16* Ps = sm + 2 * 64 * LSTR + w * 32 * LSTR;   // wave-private
  const int lane = threadIdx.x & 63;
  const int quad = lane >> 4, l15 = lane & 15;
  // T1: bijective XCD-chunk swizzle (linear id round-robins XCDs)
  const int Lraw = blockIdx.x;
  const int swz  = (Lraw & 7) * (NBLK / 8) + (Lraw >> 3);
  const int qt = swz & 31;        // SEQ/128 = 32
  const int bh = swz >> 5;
  const int b  = bh / NH;
  const int h  = bh - b * NH;
  const size_t rowb = (size_t)b * SEQ * NQKV + (size_t)h * HD;  // + s*NQKV per token

  // Q fragments (A-layout) straight from global into registers, kept all loop
  f16x8 qreg[2][2];
  #pragma unroll
  for (int mt = 0; mt < 2; mt++)
    #pragma unroll
    for (int ks = 0; ks < 2; ks++) {
      const int row = qt * 128 + w * 32 + mt * 16 + l15;
      qreg[mt][ks] = *(const f16x8*)(QKV + rowb + (size_t)row * NQKV + ks * 32 + quad * 8);
    }

  // ones B-fragment: column n==0 of the ghost V-tile is all ones
  f16x8 onesF;
  {
    const _Float16 one = (_Float16)(l15 == 0 ? 1.0f : 0.0f);
    #pragma unroll
    for (int j = 0; j < 8; j++) onesF[j] = one;
  }

  f32x4 o[2][4], o4[2];
  #pragma unroll
  for (int mt = 0; mt < 2; mt++) {
    o4[mt] = (f32x4){0.f, 0.f, 0.f, 0.f};
    #pragma unroll
    for (int t = 0; t < 4; t++) o[mt][t] = (f32x4){0.f, 0.f, 0.f, 0.f};
  }

  for (int kt = 0; kt < SEQ / 64; ++kt) {
    __syncthreads();
    // stage K tile (64 keys x 64 d)
    #pragma unroll
    for (int i = 0; i < 2; i++) {
      const int chunk = threadIdx.x + i * 256;
      const int r = chunk >> 3, c0 = (chunk & 7) * 8;
      *(uint4*)&Ks[r * LSTR + c0] =
          *(const uint4*)(QKV + rowb + (size_t)(kt * 64 + r) * NQKV + DIM + c0);
    }
    // stage V tile transposed: Vts[d][key]
    #pragma unroll
    for (int i = 0; i < 2; i++) {
      const int c0 = w * 16 + i * 8;
      union { uint4 v; _Float16 u[8]; } d;
      d.v = *(const uint4*)(QKV + rowb + (size_t)(kt * 64 + lane) * NQKV + 2 * DIM + c0);
      #pragma unroll
      for (int j = 0; j < 8; j++) Vts[(c0 + j) * LSTR + lane] = d.u[j];
    }
    __syncthreads();

    // S = Q K^T : 32 q-rows x 64 keys per wave (scores already in log2 domain)
    f32x4 sacc[2][4];
    #pragma unroll
    for (int mt = 0; mt < 2; mt++)
      #pragma unroll
      for (int t = 0; t < 4; t++) sacc[mt][t] = (f32x4){0.f, 0.f, 0.f, 0.f};
    #pragma unroll
    for (int ks = 0; ks < 2; ks++) {
      f16x8 bF[4];
      #pragma unroll
      for (int t = 0; t < 4; t++)
        bF[t] = *(const f16x8*)&Ks[(t * 16 + l15) * LSTR + ks * 32 + quad * 8];
      #pragma unroll
      for (int mt = 0; mt < 2; mt++)
        #pragma unroll
        for (int t = 0; t < 4; t++)
          sacc[mt][t] = __builtin_amdgcn_mfma_f32_16x16x32_f16(qreg[mt][ks], bF[t], sacc[mt][t], 0, 0, 0);
    }

    // p = exp2(score); write fp16 P to wave-private LDS (no max, no rescale)
    #pragma unroll
    for (int mt = 0; mt < 2; mt++)
      #pragma unroll
      for (int t = 0; t < 4; t++)
        #pragma unroll
        for (int r = 0; r < 4; r++) {
          const _Float16 ph = (_Float16)fexp2(sacc[mt][t][r]);
          Ps[(mt * 16 + quad * 4 + r) * LSTR + t * 16 + l15] = ph;
        }

    // O += P V ; Sigma p (rounded) via ones-column into o4
    #pragma unroll
    for (int ks = 0; ks < 2; ks++) {
      f16x8 pF[2];
      #pragma unroll
      for (int mt = 0; mt < 2; mt++)
        pF[mt] = *(const f16x8*)&Ps[(mt * 16 + l15) * LSTR + ks * 32 + quad * 8];
      #pragma unroll
      for (int t = 0; t < 4; t++) {
        f16x8 vF = *(const f16x8*)&Vts[(t * 16 + l15) * LSTR + ks * 32 + quad * 8];
        #pragma unroll
        for (int mt = 0; mt < 2; mt++)
          o[mt][t] = __builtin_amdgcn_mfma_f32_16x16x32_f16(pF[mt], vF, o[mt][t], 0, 0, 0);
      }
      #pragma unroll
      for (int mt = 0; mt < 2; mt++)
        o4[mt] = __builtin_amdgcn_mfma_f32_16x16x32_f16(pF[mt], onesF, o4[mt], 0, 0, 0);
    }
  }

  // epilogue: lrow = Sigma p lives at lanes l15==0 (col 0 of ones-tile)
  #pragma unroll
  for (int mt = 0; mt < 2; mt++) {
    float lrow[4];
    #pragma unroll
    for (int r = 0; r < 4; r++) lrow[r] = __shfl(o4[mt][r], lane & 48);
    #pragma unroll
    for (int t = 0; t < 4; t++)
      #pragma unroll
      for (int r = 0; r < 4; r++) {
        const int srow = qt * 128 + w * 32 + mt * 16 + quad * 4 + r;
        const int d = t * 16 + l15;
        Out[((size_t)(b * SEQ + srow)) * DIM + h * HD + d] = o[mt][t][r] / lrow[r];
      }
  }
}

// ---------------- launch --------------------------------------------------
extern "C" void kernel_launch(void* const* d_in, const int* in_sizes, int n_in,
                              void* d_out, int out_size, void* d_ws, size_t ws_size,
                              hipStream_t stream) {
  const float* X    = (const float*)d_in[0];
  const float* Cos  = (const float*)d_in[1];
  const float* Sin  = (const float*)d_in[2];
  const float* W    = (const float*)d_in[3];
  const float* Bias = (const float*)d_in[4];
  float* Out = (float*)d_out;

  char* ws = (char*)d_ws;
  _Float16* Xh  = (_Float16*)(ws);                  // 50,331,648 B
  _Float16* Wt  = (_Float16*)(ws + 50331648);       // 14,155,776 B
  _Float16* QKV = (_Float16*)(ws + 64487424);       // 150,994,944 B (end 215,482,368)

  convert_x  <<<dim3(ROWS * DIM / (8 * 256)), 256, 0, stream>>>(X, Xh);
  transpose_w<<<dim3(NQKV / 32, DIM / 32), dim3(32, 8), 0, stream>>>(W, Wt);
  qkv_gemm   <<<dim3(NQKV / 128, ROWS / 128), 256, 0, stream>>>(Xh, Wt, Bias, Cos, Sin, QKV);
  flash_attn <<<dim3(NBLK), 256, 0, stream>>>(QKV, Out);
}

// Round 5
// 1109.812 us; speedup vs baseline: 1.4217x; 1.1876x over previous
//
#include <hip/hip_runtime.h>

#define DIM   1536
#define NQKV  4608
#define NH    24
#define HD    64
#define BATCH 4
#define SEQ   4096
#define ROWS  16384   // BATCH*SEQ

typedef _Float16 f16x8 __attribute__((ext_vector_type(8)));
typedef _Float16 f16x2 __attribute__((ext_vector_type(2)));
typedef float    f32x4 __attribute__((ext_vector_type(4)));
typedef float    f32x16 __attribute__((ext_vector_type(16)));
typedef unsigned u32x2 __attribute__((ext_vector_type(2)));

__device__ __forceinline__ void gload_lds16(const void* g, void* l) {
  __builtin_amdgcn_global_load_lds(
      (const __attribute__((address_space(1))) unsigned int*)g,
      (__attribute__((address_space(3))) unsigned int*)l, 16, 0, 0);
}
__device__ __forceinline__ float fexp2(float x) {
#if __has_builtin(__builtin_amdgcn_exp2f)
  return __builtin_amdgcn_exp2f(x);
#else
  return exp2f(x);
#endif
}

// hazard-safe half-wave swap: exchanges hi-32-lane slice of a with
// lo-32-lane slice of b (per-lane: hi lanes' a <- b@(lane-32); lo lanes'
// b <- a@(lane+32)). Builtin lets the compiler insert cross-lane hazard NOPs
// (the R4 inline-asm version had no hazard handling -> garbage/NaN).
__device__ __forceinline__ void swap32(unsigned& a, unsigned& b) {
#if __has_builtin(__builtin_amdgcn_permlane32_swap)
  u32x2 r = __builtin_amdgcn_permlane32_swap(a, b, false, false);
  a = r[0]; b = r[1];
#else
  const int hi = (threadIdx.x & 63) >> 5;
  unsigned as = (unsigned)__shfl_xor((int)a, 32);
  unsigned bs = (unsigned)__shfl_xor((int)b, 32);
  unsigned na = hi ? bs : a;
  unsigned nb = hi ? b  : as;
  a = na; b = nb;
#endif
}

// scale * log2(e), folded into q inside the qkv_gemm epilogue
#define QSCALE 0.18033688011112042f

// ---------------- kernel 0: X fp32 -> fp16 --------------------------------
__global__ __launch_bounds__(256) void convert_x(const float* __restrict__ X,
                                                 _Float16* __restrict__ Xh) {
  const int i = (blockIdx.x * 256 + threadIdx.x) * 8;
  float4 a = *(const float4*)(X + i);
  float4 b = *(const float4*)(X + i + 4);
  f16x8 h;
  h[0] = (_Float16)a.x; h[1] = (_Float16)a.y; h[2] = (_Float16)a.z; h[3] = (_Float16)a.w;
  h[4] = (_Float16)b.x; h[5] = (_Float16)b.y; h[6] = (_Float16)b.z; h[7] = (_Float16)b.w;
  *(f16x8*)(Xh + i) = h;
}

// ---------------- kernel 1: W (K x N) fp32 -> Wt (N x K) fp16 -------------
__global__ __launch_bounds__(256) void transpose_w(const float* __restrict__ W,
                                                   _Float16* __restrict__ Wt) {
  __shared__ float tile[32][33];
  const int tx = threadIdx.x, ty = threadIdx.y;        // 32 x 8
  const int k0 = blockIdx.y * 32, n0 = blockIdx.x * 32;
  #pragma unroll
  for (int i = 0; i < 32; i += 8)
    tile[ty + i][tx] = W[(size_t)(k0 + ty + i) * NQKV + n0 + tx];
  __syncthreads();
  #pragma unroll
  for (int i = 0; i < 32; i += 8)
    Wt[(size_t)(n0 + ty + i) * DIM + k0 + tx] = (_Float16)tile[tx][ty + i];
}

// ---------------- kernel 2: QKV = Xh @ Wt^T + b, fused RMSNorm+RoPE -------
__global__ __launch_bounds__(256) void qkv_gemm(const _Float16* __restrict__ Xh,
                                                const _Float16* __restrict__ Wt,
                                                const float* __restrict__ Bias,
                                                const float* __restrict__ Cos,
                                                const float* __restrict__ Sin,
                                                _Float16* __restrict__ QKV) {
  __shared__ _Float16 As[128 * 64];
  __shared__ _Float16 Bs[128 * 64];
  const int w    = threadIdx.x >> 6;
  const int lane = threadIdx.x & 63;
  const int lr   = lane >> 3, lc = lane & 7;
  const int quad = lane >> 4, l15 = lane & 15;
  const int m0 = blockIdx.y * 128;
  const int n0 = blockIdx.x * 128;
  const int waveR = (w >> 1) * 64;
  const int waveC = (w & 1) * 64;

  f32x4 acc[4][4];
  #pragma unroll
  for (int i = 0; i < 4; i++)
    #pragma unroll
    for (int j = 0; j < 4; j++) acc[i][j] = (f32x4){0.f, 0.f, 0.f, 0.f};

  for (int kt = 0; kt < DIM / 64; ++kt) {
    const int k0 = kt * 64;
    #pragma unroll
    for (int i = 0; i < 4; ++i) {
      const int rr = w * 32 + i * 8;
      gload_lds16(Xh + (size_t)(m0 + rr + lr) * DIM + k0 + lc * 8, &As[rr * 64]);
      gload_lds16(Wt + (size_t)(n0 + rr + lr) * DIM + k0 + lc * 8, &Bs[rr * 64]);
    }
    __syncthreads();
    #pragma unroll
    for (int ks = 0; ks < 2; ++ks) {
      f16x8 aF[4], bF[4];
      #pragma unroll
      for (int t = 0; t < 4; t++)
        aF[t] = *(const f16x8*)&As[(waveR + t * 16 + l15) * 64 + ks * 32 + quad * 8];
      #pragma unroll
      for (int t = 0; t < 4; t++)
        bF[t] = *(const f16x8*)&Bs[(waveC + t * 16 + l15) * 64 + ks * 32 + quad * 8];
      #pragma unroll
      for (int mt = 0; mt < 4; mt++)
        #pragma unroll
        for (int nt = 0; nt < 4; nt++)
          acc[mt][nt] = __builtin_amdgcn_mfma_f32_16x16x32_f16(aF[mt], bF[nt], acc[mt][nt], 0, 0, 0);
    }
    __syncthreads();
  }

  // ---- epilogue: fused bias + RMSNorm + RoPE (Q/K), plain bias (V) -------
  const int nCol0  = n0 + waveC;          // wave's 64-col head base
  const int region = nCol0 / DIM;         // 0=Q, 1=K, 2=V (wave-uniform)

  float bias[4];
  #pragma unroll
  for (int nt = 0; nt < 4; nt++) bias[nt] = Bias[nCol0 + nt * 16 + l15];

  if (region == 2) {
    #pragma unroll
    for (int nt = 0; nt < 4; nt++) {
      const int n = nCol0 + nt * 16 + l15;
      #pragma unroll
      for (int mt = 0; mt < 4; mt++) {
        const int mBase = m0 + waveR + mt * 16 + quad * 4;
        #pragma unroll
        for (int r = 0; r < 4; r++)
          QKV[(size_t)(mBase + r) * NQKV + n] = (_Float16)(acc[mt][nt][r] + bias[nt]);
      }
    }
  } else {
    const float qsc = (region == 0) ? QSCALE : 1.0f;
    #pragma unroll
    for (int mt = 0; mt < 4; mt++) {
      const int mBase = m0 + waveR + mt * 16 + quad * 4;
      #pragma unroll
      for (int r = 0; r < 4; r++) {
        const int m = mBase + r;
        const int s = m & (SEQ - 1);
        float v[4];
        float ss = 0.f;
        #pragma unroll
        for (int nt = 0; nt < 4; nt++) {
          v[nt] = acc[mt][nt][r] + bias[nt];
          ss += v[nt] * v[nt];
        }
        #pragma unroll
        for (int off = 1; off < 16; off <<= 1) ss += __shfl_xor(ss, off);
        const float rinv = rsqrtf(ss * (1.f / 64.f) + 1e-6f);
        #pragma unroll
        for (int nt = 0; nt < 4; nt++) {
          const int d = nt * 16 + l15;
          const float c  = Cos[s * HD + d];
          const float si = Sin[s * HD + d];
          const float x  = v[nt] * rinv;
          const float xp = __shfl_xor(x, 1);
          float o = (l15 & 1) ? (x * c + xp * si) : (x * c - xp * si);
          o *= qsc;
          QKV[(size_t)m * NQKV + nCol0 + d] = (_Float16)o;
        }
      }
    }
  }
}

// ---------------- kernel 3: flash attention, in-register softmax ----------
// R5: R4 structure (32x32x16 MFMA, swapped QK^T so lane holds the P-row for
// q = lane&31; exp2 + pack f16 pairs; permlane32 half-swaps build PV
// A-fragments in registers; no Ps LDS buffer) with the two unsafe primitives
// replaced:
//   - permlane via __builtin_amdgcn_permlane32_swap (compiler handles the
//     cross-lane read-after-VALU hazard that raw inline asm does not)
//   - row-sum via plain float adds of the rounded f16 values at pack time
//     (pre-swap multiset per q across the hi-pair == post-swap; the hi0+hi1
//     reduction covers all 32 keys)
#define LSTR 72
__global__ __launch_bounds__(256) void flash_attn(const _Float16* __restrict__ QKV,
                                                  float* __restrict__ Out) {
  __shared__ __align__(16) _Float16 sm[2 * 64 * LSTR];   // K + V^T only
  _Float16* Ks  = sm;
  _Float16* Vts = sm + 64 * LSTR;
  const int w    = threadIdx.x >> 6;
  const int lane = threadIdx.x & 63;
  const int l31  = lane & 31;
  const int hi   = lane >> 5;
  const int qt = blockIdx.x;
  const int bh = blockIdx.y;
  const int b  = bh / NH;
  const int h  = bh - b * NH;
  const size_t rowb = (size_t)b * SEQ * NQKV + (size_t)h * HD;  // + s*NQKV per token

  // Q as B-operand fragments: lane(l31,hi) holds Q[q=l31][d=dw*16+hi*8+j]
  f16x8 qreg[4];
  {
    const int row = qt * 128 + w * 32 + l31;
    #pragma unroll
    for (int dw = 0; dw < 4; dw++)
      qreg[dw] = *(const f16x8*)(QKV + rowb + (size_t)row * NQKV + dw * 16 + hi * 8);
  }

  f32x16 o[2] = {};     // O accumulator: col d = dt*32+l31, row q by C-formula
  float lsum = 0.f;     // per-lane partial sum of rounded p (q = l31)

  for (int kt = 0; kt < SEQ / 64; ++kt) {
    __syncthreads();
    // stage K tile (64 keys x 64 d), row-major with pad
    #pragma unroll
    for (int i = 0; i < 2; i++) {
      const int chunk = threadIdx.x + i * 256;
      const int r = chunk >> 3, c0 = (chunk & 7) * 8;
      *(uint4*)&Ks[r * LSTR + c0] =
          *(const uint4*)(QKV + rowb + (size_t)(kt * 64 + r) * NQKV + DIM + c0);
    }
    // stage V tile transposed: Vts[d][key]
    #pragma unroll
    for (int i = 0; i < 2; i++) {
      const int c0 = w * 16 + i * 8;
      union { uint4 v; _Float16 u[8]; } d;
      d.v = *(const uint4*)(QKV + rowb + (size_t)(kt * 64 + lane) * NQKV + 2 * DIM + c0);
      #pragma unroll
      for (int j = 0; j < 8; j++) Vts[(c0 + j) * LSTR + lane] = d.u[j];
    }
    __syncthreads();

    #pragma unroll
    for (int kt32 = 0; kt32 < 2; ++kt32) {
      // S^T (32 keys x 32 q) = sum_d K[key][d] * Q[q][d]
      f32x16 sacc = {};
      #pragma unroll
      for (int dw = 0; dw < 4; dw++) {
        f16x8 kF = *(const f16x8*)&Ks[(kt32 * 32 + l31) * LSTR + dw * 16 + hi * 8];
        sacc = __builtin_amdgcn_mfma_f32_32x32x16_f16(kF, qreg[dw], sacc, 0, 0, 0);
      }

      // p = exp2(score) (log2-domain scores, statically bounded); pack pairs
      // and accumulate the rounded-p row sum in the same pass.
      // Key of reg r (pre-swap) = (r&3) + 8*(r>>2) + 4*hi.
      unsigned pk[8];
      #pragma unroll
      for (int i = 0; i < 8; i++) {
        union { f16x2 h2; unsigned u; } uu;
        uu.h2[0] = (_Float16)fexp2(sacc[2 * i]);
        uu.h2[1] = (_Float16)fexp2(sacc[2 * i + 1]);
        lsum += (float)uu.h2[0] + (float)uu.h2[1];
        pk[i] = uu.u;
      }
      // hi0<->hi1 half swaps arrange pk into PV A-fragment word order:
      // after swap, lane(l31,hi) word w of window kw holds keys
      // kw*16 + hi*8 + {2w, 2w+1} of q-row l31.
      swap32(pk[0], pk[2]);
      swap32(pk[1], pk[3]);
      swap32(pk[4], pk[6]);
      swap32(pk[5], pk[7]);

      // O += P V for the two 16-key windows
      #pragma unroll
      for (int h16 = 0; h16 < 2; ++h16) {
        const int kw = kt32 * 2 + h16;
        union { unsigned u[4]; f16x8 f; } pa;
        pa.u[0] = pk[h16 * 4 + 0];
        pa.u[1] = pk[h16 * 4 + 1];
        pa.u[2] = pk[h16 * 4 + 2];
        pa.u[3] = pk[h16 * 4 + 3];
        #pragma unroll
        for (int dt = 0; dt < 2; ++dt) {
          f16x8 vF = *(const f16x8*)&Vts[(dt * 32 + l31) * LSTR + kw * 16 + hi * 8];
          o[dt] = __builtin_amdgcn_mfma_f32_32x32x16_f16(pa.f, vF, o[dt], 0, 0, 0);
        }
      }
    }
  }

  // epilogue: full row sum = hi0 partial + hi1 partial, held at lane l31=q
  const float ls = lsum + __shfl_xor(lsum, 32);
  #pragma unroll
  for (int r = 0; r < 16; r++) {
    const int q = (r & 3) + 8 * (r >> 2) + 4 * hi;
    const float lrow = __shfl(ls, q);   // lane q (<32) holds sum for q-row q
    const int srow = qt * 128 + w * 32 + q;
    #pragma unroll
    for (int dt = 0; dt < 2; dt++)
      Out[((size_t)(b * SEQ + srow)) * DIM + h * HD + dt * 32 + l31] = o[dt][r] / lrow;
  }
}

// ---------------- launch --------------------------------------------------
extern "C" void kernel_launch(void* const* d_in, const int* in_sizes, int n_in,
                              void* d_out, int out_size, void* d_ws, size_t ws_size,
                              hipStream_t stream) {
  const float* X    = (const float*)d_in[0];
  const float* Cos  = (const float*)d_in[1];
  const float* Sin  = (const float*)d_in[2];
  const float* W    = (const float*)d_in[3];
  const float* Bias = (const float*)d_in[4];
  float* Out = (float*)d_out;

  char* ws = (char*)d_ws;
  _Float16* Xh  = (_Float16*)(ws);                  // 50,331,648 B
  _Float16* Wt  = (_Float16*)(ws + 50331648);       // 14,155,776 B
  _Float16* QKV = (_Float16*)(ws + 64487424);       // 150,994,944 B (end 215,482,368)

  convert_x  <<<dim3(ROWS * DIM / (8 * 256)), 256, 0, stream>>>(X, Xh);
  transpose_w<<<dim3(NQKV / 32, DIM / 32), dim3(32, 8), 0, stream>>>(W, Wt);
  qkv_gemm   <<<dim3(NQKV / 128, ROWS / 128), 256, 0, stream>>>(Xh, Wt, Bias, Cos, Sin, QKV);
  flash_attn <<<dim3(SEQ / 128, BATCH * NH), 256, 0, stream>>>(QKV, Out);
}

// Round 7
// 1055.608 us; speedup vs baseline: 1.4947x; 1.0513x over previous
//
#include <hip/hip_runtime.h>

#define DIM   1536
#define NQKV  4608
#define NH    24
#define HD    64
#define BATCH 4
#define SEQ   4096
#define ROWS  16384   // BATCH*SEQ

typedef _Float16 f16x8 __attribute__((ext_vector_type(8)));
typedef _Float16 f16x2 __attribute__((ext_vector_type(2)));
typedef __fp16   h16x2 __attribute__((ext_vector_type(2)));   // cvt_pkrtz return type
typedef float    f32x4 __attribute__((ext_vector_type(4)));
typedef float    f32x16 __attribute__((ext_vector_type(16)));
typedef unsigned u32x2 __attribute__((ext_vector_type(2)));

__device__ __forceinline__ void gload_lds16(const void* g, void* l) {
  __builtin_amdgcn_global_load_lds(
      (const __attribute__((address_space(1))) unsigned int*)g,
      (__attribute__((address_space(3))) unsigned int*)l, 16, 0, 0);
}
__device__ __forceinline__ float fexp2(float x) {
#if __has_builtin(__builtin_amdgcn_exp2f)
  return __builtin_amdgcn_exp2f(x);
#else
  return exp2f(x);
#endif
}

// hazard-safe half-wave swap (see R5 note: builtin gets compiler-inserted
// cross-lane hazard NOPs; raw inline asm did not -> NaN).
__device__ __forceinline__ void swap32(unsigned& a, unsigned& b) {
#if __has_builtin(__builtin_amdgcn_permlane32_swap)
  u32x2 r = __builtin_amdgcn_permlane32_swap(a, b, false, false);
  a = r[0]; b = r[1];
#else
  const int hi = (threadIdx.x & 63) >> 5;
  unsigned as = (unsigned)__shfl_xor((int)a, 32);
  unsigned bs = (unsigned)__shfl_xor((int)b, 32);
  unsigned na = hi ? bs : a;
  unsigned nb = hi ? b  : as;
  a = na; b = nb;
#endif
}

// scale * log2(e), folded into q inside the qkv_gemm epilogue
#define QSCALE 0.18033688011112042f

// ---------------- kernel 0: X fp32 -> fp16 --------------------------------
__global__ __launch_bounds__(256) void convert_x(const float* __restrict__ X,
                                                 _Float16* __restrict__ Xh) {
  const int i = (blockIdx.x * 256 + threadIdx.x) * 8;
  float4 a = *(const float4*)(X + i);
  float4 b = *(const float4*)(X + i + 4);
  f16x8 h;
  h[0] = (_Float16)a.x; h[1] = (_Float16)a.y; h[2] = (_Float16)a.z; h[3] = (_Float16)a.w;
  h[4] = (_Float16)b.x; h[5] = (_Float16)b.y; h[6] = (_Float16)b.z; h[7] = (_Float16)b.w;
  *(f16x8*)(Xh + i) = h;
}

// ---------------- kernel 1: W (K x N) fp32 -> Wt (N x K) fp16 -------------
__global__ __launch_bounds__(256) void transpose_w(const float* __restrict__ W,
                                                   _Float16* __restrict__ Wt) {
  __shared__ float tile[32][33];
  const int tx = threadIdx.x, ty = threadIdx.y;        // 32 x 8
  const int k0 = blockIdx.y * 32, n0 = blockIdx.x * 32;
  #pragma unroll
  for (int i = 0; i < 32; i += 8)
    tile[ty + i][tx] = W[(size_t)(k0 + ty + i) * NQKV + n0 + tx];
  __syncthreads();
  #pragma unroll
  for (int i = 0; i < 32; i += 8)
    Wt[(size_t)(n0 + ty + i) * DIM + k0 + tx] = (_Float16)tile[tx][ty + i];
}

// ---------------- kernel 2: QKV = Xh @ Wt^T + b, fused RMSNorm+RoPE -------
__global__ __launch_bounds__(256) void qkv_gemm(const _Float16* __restrict__ Xh,
                                                const _Float16* __restrict__ Wt,
                                                const float* __restrict__ Bias,
                                                const float* __restrict__ Cos,
                                                const float* __restrict__ Sin,
                                                _Float16* __restrict__ QKV) {
  __shared__ _Float16 As[128 * 64];
  __shared__ _Float16 Bs[128 * 64];
  const int w    = threadIdx.x >> 6;
  const int lane = threadIdx.x & 63;
  const int lr   = lane >> 3, lc = lane & 7;
  const int quad = lane >> 4, l15 = lane & 15;
  const int m0 = blockIdx.y * 128;
  const int n0 = blockIdx.x * 128;
  const int waveR = (w >> 1) * 64;
  const int waveC = (w & 1) * 64;

  f32x4 acc[4][4];
  #pragma unroll
  for (int i = 0; i < 4; i++)
    #pragma unroll
    for (int j = 0; j < 4; j++) acc[i][j] = (f32x4){0.f, 0.f, 0.f, 0.f};

  for (int kt = 0; kt < DIM / 64; ++kt) {
    const int k0 = kt * 64;
    #pragma unroll
    for (int i = 0; i < 4; ++i) {
      const int rr = w * 32 + i * 8;
      gload_lds16(Xh + (size_t)(m0 + rr + lr) * DIM + k0 + lc * 8, &As[rr * 64]);
      gload_lds16(Wt + (size_t)(n0 + rr + lr) * DIM + k0 + lc * 8, &Bs[rr * 64]);
    }
    __syncthreads();
    #pragma unroll
    for (int ks = 0; ks < 2; ++ks) {
      f16x8 aF[4], bF[4];
      #pragma unroll
      for (int t = 0; t < 4; t++)
        aF[t] = *(const f16x8*)&As[(waveR + t * 16 + l15) * 64 + ks * 32 + quad * 8];
      #pragma unroll
      for (int t = 0; t < 4; t++)
        bF[t] = *(const f16x8*)&Bs[(waveC + t * 16 + l15) * 64 + ks * 32 + quad * 8];
      #pragma unroll
      for (int mt = 0; mt < 4; mt++)
        #pragma unroll
        for (int nt = 0; nt < 4; nt++)
          acc[mt][nt] = __builtin_amdgcn_mfma_f32_16x16x32_f16(aF[mt], bF[nt], acc[mt][nt], 0, 0, 0);
    }
    __syncthreads();
  }

  // ---- epilogue: fused bias + RMSNorm + RoPE (Q/K), plain bias (V) -------
  const int nCol0  = n0 + waveC;          // wave's 64-col head base
  const int region = nCol0 / DIM;         // 0=Q, 1=K, 2=V (wave-uniform)

  float bias[4];
  #pragma unroll
  for (int nt = 0; nt < 4; nt++) bias[nt] = Bias[nCol0 + nt * 16 + l15];

  if (region == 2) {
    #pragma unroll
    for (int nt = 0; nt < 4; nt++) {
      const int n = nCol0 + nt * 16 + l15;
      #pragma unroll
      for (int mt = 0; mt < 4; mt++) {
        const int mBase = m0 + waveR + mt * 16 + quad * 4;
        #pragma unroll
        for (int r = 0; r < 4; r++)
          QKV[(size_t)(mBase + r) * NQKV + n] = (_Float16)(acc[mt][nt][r] + bias[nt]);
      }
    }
  } else {
    const float qsc = (region == 0) ? QSCALE : 1.0f;
    #pragma unroll
    for (int mt = 0; mt < 4; mt++) {
      const int mBase = m0 + waveR + mt * 16 + quad * 4;
      #pragma unroll
      for (int r = 0; r < 4; r++) {
        const int m = mBase + r;
        const int s = m & (SEQ - 1);
        float v[4];
        float ss = 0.f;
        #pragma unroll
        for (int nt = 0; nt < 4; nt++) {
          v[nt] = acc[mt][nt][r] + bias[nt];
          ss += v[nt] * v[nt];
        }
        #pragma unroll
        for (int off = 1; off < 16; off <<= 1) ss += __shfl_xor(ss, off);
        const float rinv = rsqrtf(ss * (1.f / 64.f) + 1e-6f);
        #pragma unroll
        for (int nt = 0; nt < 4; nt++) {
          const int d = nt * 16 + l15;
          const float c  = Cos[s * HD + d];
          const float si = Sin[s * HD + d];
          const float x  = v[nt] * rinv;
          const float xp = __shfl_xor(x, 1);
          float o = (l15 & 1) ? (x * c + xp * si) : (x * c - xp * si);
          o *= qsc;
          QKV[(size_t)m * NQKV + nCol0 + d] = (_Float16)o;
        }
      }
    }
  }
}

// ---------------- kernel 3: flash attention, in-register softmax ----------
// R7 (= R6 with the cvt_pkrtz return-type fix): VALU diet on the softmax
// path (R5 counters: VALUBusy 67% vs MfmaUtil 34% — VALU-bound):
//   - pack via v_cvt_pkrtz_f16_f32 builtin (1 op per float pair, replaces
//     2 cvt + 1 pack); builtin returns __fp16x2, viewed through a union
//   - row-sum via v_dot2_f32_f16 on the SAME packed register PV consumes
//     (replaces 2 cvt + 2 add per pair); two accumulators break the chain
#define LSTR 72
__global__ __launch_bounds__(256) void flash_attn(const _Float16* __restrict__ QKV,
                                                  float* __restrict__ Out) {
  __shared__ __align__(16) _Float16 sm[2 * 64 * LSTR];   // K + V^T only
  _Float16* Ks  = sm;
  _Float16* Vts = sm + 64 * LSTR;
  const int w    = threadIdx.x >> 6;
  const int lane = threadIdx.x & 63;
  const int l31  = lane & 31;
  const int hi   = lane >> 5;
  const int qt = blockIdx.x;
  const int bh = blockIdx.y;
  const int b  = bh / NH;
  const int h  = bh - b * NH;
  const size_t rowb = (size_t)b * SEQ * NQKV + (size_t)h * HD;  // + s*NQKV per token

  // Q as B-operand fragments: lane(l31,hi) holds Q[q=l31][d=dw*16+hi*8+j]
  f16x8 qreg[4];
  {
    const int row = qt * 128 + w * 32 + l31;
    #pragma unroll
    for (int dw = 0; dw < 4; dw++)
      qreg[dw] = *(const f16x8*)(QKV + rowb + (size_t)row * NQKV + dw * 16 + hi * 8);
  }

  f32x16 o[2] = {};           // O accumulator: col d = dt*32+l31, row q by C-formula
  float ls0 = 0.f, ls1 = 0.f; // per-lane partial sums of rounded p (q = l31)
  const f16x2 one2 = {(_Float16)1.0f, (_Float16)1.0f};

  for (int kt = 0; kt < SEQ / 64; ++kt) {
    __syncthreads();
    // stage K tile (64 keys x 64 d), row-major with pad
    #pragma unroll
    for (int i = 0; i < 2; i++) {
      const int chunk = threadIdx.x + i * 256;
      const int r = chunk >> 3, c0 = (chunk & 7) * 8;
      *(uint4*)&Ks[r * LSTR + c0] =
          *(const uint4*)(QKV + rowb + (size_t)(kt * 64 + r) * NQKV + DIM + c0);
    }
    // stage V tile transposed: Vts[d][key]
    #pragma unroll
    for (int i = 0; i < 2; i++) {
      const int c0 = w * 16 + i * 8;
      union { uint4 v; _Float16 u[8]; } d;
      d.v = *(const uint4*)(QKV + rowb + (size_t)(kt * 64 + lane) * NQKV + 2 * DIM + c0);
      #pragma unroll
      for (int j = 0; j < 8; j++) Vts[(c0 + j) * LSTR + lane] = d.u[j];
    }
    __syncthreads();

    #pragma unroll
    for (int kt32 = 0; kt32 < 2; ++kt32) {
      // S^T (32 keys x 32 q) = sum_d K[key][d] * Q[q][d]
      f32x16 sacc = {};
      #pragma unroll
      for (int dw = 0; dw < 4; dw++) {
        f16x8 kF = *(const f16x8*)&Ks[(kt32 * 32 + l31) * LSTR + dw * 16 + hi * 8];
        sacc = __builtin_amdgcn_mfma_f32_32x32x16_f16(kF, qreg[dw], sacc, 0, 0, 0);
      }

      // p = exp2(score) (log2-domain scores, statically bounded).
      // cvt_pkrtz packs each float pair in one VALU op; fdot2 accumulates the
      // rounded-p row sum from the same packed register PV will consume.
      unsigned pk[8];
      #pragma unroll
      for (int i = 0; i < 8; i++) {
        union { h16x2 h2; f16x2 f2; unsigned u; } uu;
#if __has_builtin(__builtin_amdgcn_cvt_pkrtz)
        uu.h2 = __builtin_amdgcn_cvt_pkrtz(fexp2(sacc[2 * i]), fexp2(sacc[2 * i + 1]));
#else
        uu.f2[0] = (_Float16)fexp2(sacc[2 * i]);
        uu.f2[1] = (_Float16)fexp2(sacc[2 * i + 1]);
#endif
        pk[i] = uu.u;
#if __has_builtin(__builtin_amdgcn_fdot2)
        if (i & 1) ls1 = __builtin_amdgcn_fdot2(uu.f2, one2, ls1, false);
        else       ls0 = __builtin_amdgcn_fdot2(uu.f2, one2, ls0, false);
#else
        if (i & 1) ls1 += (float)uu.f2[0] + (float)uu.f2[1];
        else       ls0 += (float)uu.f2[0] + (float)uu.f2[1];
#endif
      }
      // hi0<->hi1 half swaps arrange pk into PV A-fragment word order:
      // after swap, lane(l31,hi) word w of window kw holds keys
      // kw*16 + hi*8 + {2w, 2w+1} of q-row l31.
      swap32(pk[0], pk[2]);
      swap32(pk[1], pk[3]);
      swap32(pk[4], pk[6]);
      swap32(pk[5], pk[7]);

      // O += P V for the two 16-key windows
      #pragma unroll
      for (int h16 = 0; h16 < 2; ++h16) {
        const int kw = kt32 * 2 + h16;
        union { unsigned u[4]; f16x8 f; } pa;
        pa.u[0] = pk[h16 * 4 + 0];
        pa.u[1] = pk[h16 * 4 + 1];
        pa.u[2] = pk[h16 * 4 + 2];
        pa.u[3] = pk[h16 * 4 + 3];
        #pragma unroll
        for (int dt = 0; dt < 2; ++dt) {
          f16x8 vF = *(const f16x8*)&Vts[(dt * 32 + l31) * LSTR + kw * 16 + hi * 8];
          o[dt] = __builtin_amdgcn_mfma_f32_32x32x16_f16(pa.f, vF, o[dt], 0, 0, 0);
        }
      }
    }
  }

  // epilogue: full row sum = hi0 partial + hi1 partial, held at lane l31=q
  const float lsum = ls0 + ls1;
  const float ls = lsum + __shfl_xor(lsum, 32);
  #pragma unroll
  for (int r = 0; r < 16; r++) {
    const int q = (r & 3) + 8 * (r >> 2) + 4 * hi;
    const float lrow = __shfl(ls, q);   // lane q (<32) holds sum for q-row q
    const int srow = qt * 128 + w * 32 + q;
    #pragma unroll
    for (int dt = 0; dt < 2; dt++)
      Out[((size_t)(b * SEQ + srow)) * DIM + h * HD + dt * 32 + l31] = o[dt][r] / lrow;
  }
}

// ---------------- launch --------------------------------------------------
extern "C" void kernel_launch(void* const* d_in, const int* in_sizes, int n_in,
                              void* d_out, int out_size, void* d_ws, size_t ws_size,
                              hipStream_t stream) {
  const float* X    = (const float*)d_in[0];
  const float* Cos  = (const float*)d_in[1];
  const float* Sin  = (const float*)d_in[2];
  const float* W    = (const float*)d_in[3];
  const float* Bias = (const float*)d_in[4];
  float* Out = (float*)d_out;

  char* ws = (char*)d_ws;
  _Float16* Xh  = (_Float16*)(ws);                  // 50,331,648 B
  _Float16* Wt  = (_Float16*)(ws + 50331648);       // 14,155,776 B
  _Float16* QKV = (_Float16*)(ws + 64487424);       // 150,994,944 B (end 215,482,368)

  convert_x  <<<dim3(ROWS * DIM / (8 * 256)), 256, 0, stream>>>(X, Xh);
  transpose_w<<<dim3(NQKV / 32, DIM / 32), dim3(32, 8), 0, stream>>>(W, Wt);
  qkv_gemm   <<<dim3(NQKV / 128, ROWS / 128), 256, 0, stream>>>(Xh, Wt, Bias, Cos, Sin, QKV);
  flash_attn <<<dim3(SEQ / 128, BATCH * NH), 256, 0, stream>>>(QKV, Out);
}